// Round 16
// baseline (1806.954 us; speedup 1.0000x reference)
//
#include <hip/hip_runtime.h>
#include <hip/hip_fp16.h>
#include <hip/hip_bf16.h>

typedef __attribute__((ext_vector_type(8))) short bf16x8;
typedef __attribute__((ext_vector_type(4))) float f32x4;
typedef __attribute__((ext_vector_type(2))) __fp16 f16x2;

#define L2E  1.4426950408889634f
#define L2E2 2.8853901817779268f

__device__ __forceinline__ short f2bf(float f) {
    unsigned u = __builtin_bit_cast(unsigned, f);
    unsigned r = (u + 0x7FFFu + ((u >> 16) & 1u)) >> 16;
    return (short)r;
}
__device__ __forceinline__ float fast_rcp(float x) {
    return __builtin_amdgcn_rcpf(x);
}
// weights/inputs prescaled by log2e (z,r) / 2*log2e (h) -> raw exp2
__device__ __forceinline__ float exp2n(float x) {
    return __builtin_amdgcn_exp2f(-x);
}
// pack: returns {a.lanes[0:31], b.lanes[0:31] -> lanes[32:63]} (element 0 of
// the HW swap result). Builtin (not raw asm) so the compiler inserts the
// required VALU->permlane wait states.
__device__ __forceinline__ float pl32_lo(float a, float b) {
    auto r = __builtin_amdgcn_permlane32_swap(
        __builtin_bit_cast(int, a), __builtin_bit_cast(int, b), false, false);
    return __builtin_bit_cast(float, r[0]);
}

// ---------------------------------------------------------------------------
// Prep: transpose + convert weights to bf16, PRESCALED (z/r x log2e,
// h x 2log2e). Numerics proven in R13 (passed, absmax 0.0112).
// ---------------------------------------------------------------------------
__global__ __launch_bounds__(256) void prep_kernel(
    const float* __restrict__ kf, const float* __restrict__ kb,
    const float* __restrict__ rf, const float* __restrict__ rb,
    short* __restrict__ kT, short* __restrict__ rTf, short* __restrict__ rTb)
{
    int idx = blockIdx.x * 256 + threadIdx.x;   // 0 .. 1536*256-1
    int n = idx >> 8;
    int k = idx & 255;
    const float* src = (n < 768) ? kf : kb;
    int nn = (n < 768) ? n : (n - 768);
    float sc = (nn < 512) ? L2E : L2E2;
    kT[idx] = f2bf(src[k * 768 + nn] * sc);
    if (n < 768) {
        float sc2 = (n < 512) ? L2E : L2E2;
        rTf[idx] = f2bf(rf[k * 768 + n] * sc2);
        rTb[idx] = f2bf(rb[k * 768 + n] * sc2);
    }
}

// ---------------------------------------------------------------------------
// Projection GEMM, M=8 PERMUTED layout + R15-style packed dwordx2 stores.
// Element (b = bgrp*8 + rowloc, t, col nn):
//   lane_t = ((cg2>>4)&1)*32 + (rowloc>>2)*16 + (cg2&15), slot = rowloc&3,
//   w-slot = cg2>>5, cg2 = nn&255.
//   region16 (64MB/dir): [bgrp(8)][t(1024)][w(8)][lane(64)][8 halves] (xz,xr)
//   region8  (32MB/dir, +64MB): [bgrp][t][w][lane][4 halves] (xh)
// Block = {4 batch rows (bgrp, hi_row) x 16 t} x 128 cols -> acc[i] spans the
// 4 slots of one chunk -> one packed uint2 store per j (RTZ f16).
// ---------------------------------------------------------------------------
__global__ __launch_bounds__(256) void proj_kernel(
    const float* __restrict__ x, const short* __restrict__ kT,
    const float* __restrict__ bias_f, const float* __restrict__ bias_b,
    char* __restrict__ xwp_f, char* __restrict__ xwp_b)
{
    __shared__ short lA[64][264];
    __shared__ short lB[128][264];

    const int tid = threadIdx.x;
    const int bt = blockIdx.x;             // 0..1023
    const int tbase16 = (bt >> 4) * 16;
    const int bgrp   = (bt & 15) >> 1;     // 0..7
    const int hi_row = bt & 1;             // 0/1
    const int n0 = blockIdx.y * 128;

    // stage A: 64 rows = (b_loc = r&3, t_loc = r>>2)
#pragma unroll
    for (int rep = 0; rep < 16; ++rep) {
        int lin = rep * 256 + tid;
        int r = lin >> 6;
        int c4 = lin & 63;
        int bb = bgrp * 8 + hi_row * 4 + (r & 3);
        int tt = tbase16 + (r >> 2);
        float4 v = *(const float4*)(x + ((size_t)bb * 1024 + tt) * 256 + c4 * 4);
        short4 s;
        s.x = f2bf(v.x); s.y = f2bf(v.y); s.z = f2bf(v.z); s.w = f2bf(v.w);
        *(short4*)&lA[r][c4 * 4] = s;
    }
#pragma unroll
    for (int rep = 0; rep < 16; ++rep) {
        int lin = rep * 256 + tid;
        int r = lin >> 5;
        int c8 = lin & 31;
        uint4 v = *(const uint4*)(kT + (size_t)(n0 + r) * 256 + c8 * 8);
        *(uint4*)&lB[r][c8 * 8] = v;
    }
    __syncthreads();

    const int w = tid >> 6, l = tid & 63;
    const int l15 = l & 15, hi = l >> 4;

    bf16x8 a[8];
#pragma unroll
    for (int kt = 0; kt < 8; ++kt)
        a[kt] = *(const bf16x8*)&lA[w * 16 + l15][kt * 32 + hi * 8];

    const int t_row = tbase16 + w * 4 + hi;

#pragma unroll
    for (int j = 0; j < 8; ++j) {
        f32x4 acc = {0.f, 0.f, 0.f, 0.f};
#pragma unroll
        for (int kt = 0; kt < 8; ++kt) {
            bf16x8 b = *(const bf16x8*)&lB[j * 16 + l15][kt * 32 + hi * 8];
            acc = __builtin_amdgcn_mfma_f32_16x16x32_bf16(a[kt], b, acc, 0, 0, 0);
        }
        int ng   = n0 + j * 16;            // uniform per j
        int dirb = ng >= 768;
        int nn0  = ng - (dirb ? 768 : 0);
        int g    = nn0 >> 8;               // 0=z, 1=r, 2=h
        int cg2  = nn0 & 255;
        int wtj  = cg2 >> 5;
        int tb   = (cg2 >> 4) & 1;
        int lane_t = tb * 32 + hi_row * 16 + l15;
        const float* bias = dirb ? bias_b : bias_f;
        char* basep = dirb ? xwp_b : xwp_f;
        int nn = nn0 + l15;
        float sc = (nn < 512) ? L2E : L2E2;
        float badd = (bias[nn] + ((nn < 512) ? bias[768 + nn] : 0.f)) * sc;

        f16x2 lo2 = __builtin_amdgcn_cvt_pkrtz(acc[0] + badd, acc[1] + badd);
        f16x2 hi2 = __builtin_amdgcn_cvt_pkrtz(acc[2] + badd, acc[3] + badd);
        uint2 pk;
        pk.x = __builtin_bit_cast(unsigned, lo2);
        pk.y = __builtin_bit_cast(unsigned, hi2);

        if (g < 2) {
            *(uint2*)(basep + ((size_t)bgrp << 23) + ((size_t)t_row << 13)
                      + (wtj << 10) + (lane_t << 4) + (g * 8)) = pk;
        } else {
            *(uint2*)(basep + 67108864u + ((size_t)bgrp << 22)
                      + ((size_t)t_row << 12) + (wtj << 9) + (lane_t << 3)) = pk;
        }
    }
}

// ---------------------------------------------------------------------------
// Recurrence, BATCH-SPLIT: 16 blocks (2 dir x 8 groups of 8 batch rows),
// 512 threads = 8 waves. Wave w owns cols [32w,32w+32) as two 16-col tiles.
// M=8; after the MFMA phase the two tiles' valid outputs (rows 0-7, lanes
// 0-31) are PACKED full-width via __builtin_amdgcn_permlane32_swap (builtin,
// NOT raw asm -> compiler inserts the VALU->permlane wait states that the
// R11/R12 inline-asm version skipped). Post-pack lane identity: tile = hi>>1,
// cme = w*32 + tile*16 + l15, rows (hi&1)*4..+3 -> ONE dense gate pass.
// Weights prescaled -> raw exp2 gates; b1h in acc init. 42 B-frags resident,
// 6 in LDS. xw prefetched 1 step ahead. One lgkm-only barrier per step.
// ---------------------------------------------------------------------------
#define MFMA_BF16(A, B, C) __builtin_amdgcn_mfma_f32_16x16x32_bf16(A, B, C, 0, 0, 0)

#define GRU_STEP(PR, PW, XC16, XC8, XN16, XN8)                               \
  {                                                                          \
    XN16 = *(const uint4*)xp16;  xp16 += step16;                             \
    XN8  = *(const uint2*)xp8;   xp8  += step8;                              \
    unsigned bb = 0;                                                         \
    asm volatile("" : "+v"(bb));      /* defeat cross-step LDS-read hoist */ \
    f32x4 a0z={0.f,0.f,0.f,0.f}, a0r={0.f,0.f,0.f,0.f};                      \
    f32x4 a0h={b1h0,b1h0,b1h0,b1h0};                                         \
    f32x4 a1z={0.f,0.f,0.f,0.f}, a1r={0.f,0.f,0.f,0.f};                      \
    f32x4 a1h={b1h1,b1h1,b1h1,b1h1};                                         \
    _Pragma("unroll") for (int kt = 0; kt < 8; ++kt) {                       \
      bf16x8 aq = *(const bf16x8*)((const char*)hfrag + (PR)*8192            \
                                   + kt * 1024 + l * 16);                    \
      bf16x8 bh0v, bh1v;                                                     \
      if (kt < 5) { bh0v = Bh0[kt]; bh1v = Bh1[kt]; }                        \
      else {                                                                 \
        bh0v = *(const bf16x8*)(bfragc + bb + (kt - 5) * 8192                \
                                + w * 1024 + l * 16);                        \
        bh1v = *(const bf16x8*)(bfragc + bb + 24576 + (kt - 5) * 8192        \
                                + w * 1024 + l * 16);                        \
      }                                                                      \
      a0z = MFMA_BF16(aq, Bz0[kt], a0z);                                     \
      a0r = MFMA_BF16(aq, Br0[kt], a0r);                                     \
      a0h = MFMA_BF16(aq, bh0v,    a0h);                                     \
      a1z = MFMA_BF16(aq, Bz1[kt], a1z);                                     \
      a1r = MFMA_BF16(aq, Br1[kt], a1r);                                     \
      a1h = MFMA_BF16(aq, bh1v,    a1h);                                     \
    }                                                                        \
    _Pragma("unroll") for (int i = 0; i < 4; ++i) {                          \
      a0z[i] = pl32_lo(a0z[i], a1z[i]);                                      \
      a0r[i] = pl32_lo(a0r[i], a1r[i]);                                      \
      a0h[i] = pl32_lo(a0h[i], a1h[i]);                                      \
    }                                                                        \
    const __half* hx  = (const __half*)&XC16;                                \
    const __half* hx8 = (const __half*)&XC8;                                 \
    float hn[4];                                                             \
    _Pragma("unroll") for (int i = 0; i < 4; ++i) {                          \
      float az  = __half2float(hx[i])     + a0z[i];                          \
      float ar  = __half2float(hx[4 + i]) + a0r[i];                          \
      float zi  = fast_rcp(1.f + exp2n(az));                                 \
      float rri = fast_rcp(1.f + exp2n(ar));                                 \
      float pre = __fmaf_rn(rri, a0h[i], __half2float(hx8[i]));              \
      float q   = fast_rcp(1.f + exp2n(pre));                                \
      float hh  = 2.f * q - 1.f;                                             \
      float h2  = hh + zi * (hold[i] - hh);                                  \
      hold[i] = h2;  hn[i] = h2;                                             \
      opbase[i * 524288] = h2;                                               \
    }                                                                        \
    unsigned pk0, pk1;                                                       \
    asm("v_cvt_pk_bf16_f32 %0, %1, %2" : "=v"(pk0) : "v"(hn[0]), "v"(hn[1]));\
    asm("v_cvt_pk_bf16_f32 %0, %1, %2" : "=v"(pk1) : "v"(hn[2]), "v"(hn[3]));\
    {                                                                        \
      char* hb = (char*)hfrag + (PW)*8192 + wb;                              \
      *(short*)(hb)      = (short)(pk0 & 0xffff);                            \
      *(short*)(hb + 16) = (short)(pk0 >> 16);                               \
      *(short*)(hb + 32) = (short)(pk1 & 0xffff);                            \
      *(short*)(hb + 48) = (short)(pk1 >> 16);                               \
    }                                                                        \
    opbase += ostep;                                                         \
    asm volatile("s_waitcnt lgkmcnt(0)\n\ts_barrier" ::: "memory");          \
  }

__global__ __launch_bounds__(512) void gru_kernel(
    const char* __restrict__ xwp_f, const char* __restrict__ xwp_b,
    const short* __restrict__ recT_f, const short* __restrict__ recT_b,
    const float* __restrict__ bias_f, const float* __restrict__ bias_b,
    float* __restrict__ out)
{
    __shared__ short hfrag[2][8][64][8];       // h in A-frag layout, 16KB
    __shared__ short bfrag[2][3][8][64][8];    // Bh tails (2 tiles x kt5..7), 48KB

    const int tid = threadIdx.x;
    const int w = tid >> 6, l = tid & 63;      // w in 0..7
    const int l15 = l & 15, hi = l >> 4;
    const int dir  = blockIdx.x >> 3;
    const int bgrp = blockIdx.x & 7;

    const char*  xwp  = dir ? xwp_b  : xwp_f;
    const short* recT = dir ? recT_b : recT_f;
    const float* bias = dir ? bias_b : bias_f;

    const int cg0 = w * 32 + l15;              // tile0 column (pre-pack)
    const float b1h0 = bias[1280 + cg0] * L2E2;
    const float b1h1 = bias[1280 + cg0 + 16] * L2E2;

    // post-pack lane identity: lanes<32 = tile0, lanes>=32 = tile1
    const int tile    = hi >> 1;
    const int cme     = w * 32 + tile * 16 + l15;
    const int rowbase = (hi & 1) * 4;

    // zero both hfrag buffers (rows 8-15 stay zero forever -> M=8 pad)
    ((int4*)hfrag)[tid]       = make_int4(0, 0, 0, 0);
    ((int4*)hfrag)[tid + 512] = make_int4(0, 0, 0, 0);

    // B fragments: 42 resident, 6 (Bh kt5..7 both tiles) to LDS
    const char* recTc = (const char*)recT;
    const char* bfragc = (const char*)bfrag;
    unsigned offz = (((unsigned)(cg0)       * 256u) + hi * 8u) * 2u;
    unsigned offr = (((unsigned)(256 + cg0) * 256u) + hi * 8u) * 2u;
    unsigned offh = (((unsigned)(512 + cg0) * 256u) + hi * 8u) * 2u;
    bf16x8 Bz0[8], Br0[8], Bz1[8], Br1[8], Bh0[5], Bh1[5];
#pragma unroll
    for (int kt = 0; kt < 8; ++kt) {
        Bz0[kt] = *(const bf16x8*)(recTc + offz + kt * 64);
        Br0[kt] = *(const bf16x8*)(recTc + offr + kt * 64);
        Bz1[kt] = *(const bf16x8*)(recTc + offz + 8192 + kt * 64);
        Br1[kt] = *(const bf16x8*)(recTc + offr + 8192 + kt * 64);
    }
#pragma unroll
    for (int kt = 0; kt < 5; ++kt) {
        Bh0[kt] = *(const bf16x8*)(recTc + offh + kt * 64);
        Bh1[kt] = *(const bf16x8*)(recTc + offh + 8192 + kt * 64);
    }
#pragma unroll
    for (int kt = 5; kt < 8; ++kt) {
        bf16x8 t0v = *(const bf16x8*)(recTc + offh + kt * 64);
        bf16x8 t1v = *(const bf16x8*)(recTc + offh + 8192 + kt * 64);
        *(bf16x8*)((char*)bfrag + (kt - 5) * 8192 + w * 1024 + l * 16) = t0v;
        *(bf16x8*)((char*)bfrag + 24576 + (kt - 5) * 8192 + w * 1024 + l * 16) = t1v;
    }

    // xw per-lane streaming pointers (M=8 permuted layout)
    const int t0 = dir ? 1023 : 0;
    const long step16 = dir ? -8192 : 8192;
    const long step8  = dir ? -4096 : 4096;
    const char* xp16 = xwp + ((size_t)bgrp << 23) + ((size_t)t0 << 13)
                       + (w << 10) + (l << 4);
    const char* xp8  = xwp + 67108864u + ((size_t)bgrp << 22) + ((size_t)t0 << 12)
                       + (w << 9) + (l << 3);

    // out: rows bgrp*8 + rowbase + i, column dir*256 + cme, time t
    const long ostep = dir ? -512 : 512;
    float* opbase = out + (size_t)(bgrp * 8 + rowbase) * 524288
                    + (size_t)t0 * 512 + (size_t)dir * 256 + cme;

    // h-write byte offset in hfrag buf for (rowbase, cme); +16B per row
    const unsigned wb = (unsigned)(cme >> 5) * 1024u
                      + (unsigned)((cme >> 3) & 3) * 256u
                      + (unsigned)rowbase * 16u + (unsigned)(cme & 7) * 2u;

    // prologue: load xw(t0)
    uint4 xA16, xB16;
    uint2 xA8,  xB8;
    xA16 = *(const uint4*)xp16;  xp16 += step16;
    xA8  = *(const uint2*)xp8;   xp8  += step8;

    f32x4 hold = {0.f, 0.f, 0.f, 0.f};
    __syncthreads();      // hfrag zeros + bfrag writes visible

    for (int su = 0; su < 512; ++su) {
        GRU_STEP(0, 1, xA16, xA8, xB16, xB8)
        GRU_STEP(1, 0, xB16, xB8, xA16, xA8)
    }
    // final prefetch reads t=1024 (fwd) / t=-1 (bwd): stays inside d_ws.
}

// ---------------------------------------------------------------------------
extern "C" void kernel_launch(void* const* d_in, const int* in_sizes, int n_in,
                              void* d_out, int out_size, void* d_ws, size_t ws_size,
                              hipStream_t stream) {
    const float* x   = (const float*)d_in[0];
    const float* kf  = (const float*)d_in[1];
    const float* rf  = (const float*)d_in[2];
    const float* bf_ = (const float*)d_in[3];
    const float* kb  = (const float*)d_in[4];
    const float* rb  = (const float*)d_in[5];
    const float* bb_ = (const float*)d_in[6];

    char* ws = (char*)d_ws;
    char* xwp_f = ws;                                 // 96MB permuted xw (fwd)
    char* xwp_b = ws + 100663296;                     // 96MB permuted xw (bwd)
    short* rTf  = (short*)(ws + 201326592);           // 768*256 bf16
    short* rTb  = (short*)(ws + 201719808);
    short* kT   = (short*)(ws + 202113024);           // 1536*256 bf16
    float* out  = (float*)d_out;

    hipLaunchKernelGGL(prep_kernel, dim3(1536), dim3(256), 0, stream,
                       kf, kb, rf, rb, kT, rTf, rTb);
    hipLaunchKernelGGL(proj_kernel, dim3(1024, 12), dim3(256), 0, stream,
                       x, kT, bf_, bb_, xwp_f, xwp_b);
    hipLaunchKernelGGL(gru_kernel, dim3(16), dim3(512), 0, stream,
                       xwp_f, xwp_b, rTf, rTb, bf_, bb_, out);
}

// Round 17
// 1781.060 us; speedup vs baseline: 1.0145x; 1.0145x over previous
//
#include <hip/hip_runtime.h>
#include <hip/hip_fp16.h>
#include <hip/hip_bf16.h>

typedef __attribute__((ext_vector_type(8))) short bf16x8;
typedef __attribute__((ext_vector_type(4))) float f32x4;
typedef __attribute__((ext_vector_type(2))) __fp16 f16x2;

__device__ __forceinline__ short f2bf(float f) {
    unsigned u = __builtin_bit_cast(unsigned, f);
    unsigned r = (u + 0x7FFFu + ((u >> 16) & 1u)) >> 16;
    return (short)r;
}
__device__ __forceinline__ float fast_rcp(float x) {
    return __builtin_amdgcn_rcpf(x);
}
__device__ __forceinline__ float fast_exp(float x) {
    return __builtin_amdgcn_exp2f(x * 1.4426950408889634f);
}

// ---------------------------------------------------------------------------
// Prep: transpose + convert weights to bf16.  (R8-identical)
// ---------------------------------------------------------------------------
__global__ __launch_bounds__(256) void prep_kernel(
    const float* __restrict__ kf, const float* __restrict__ kb,
    const float* __restrict__ rf, const float* __restrict__ rb,
    short* __restrict__ kT, short* __restrict__ rTf, short* __restrict__ rTb)
{
    int idx = blockIdx.x * 256 + threadIdx.x;   // 0 .. 1536*256-1
    int n = idx >> 8;
    int k = idx & 255;
    const float* src = (n < 768) ? kf : kb;
    int nn = (n < 768) ? n : (n - 768);
    kT[idx] = f2bf(src[k * 768 + nn]);
    if (n < 768) {
        rTf[idx] = f2bf(rf[k * 768 + n]);
        rTb[idx] = f2bf(rb[k * 768 + n]);
    }
}

// ---------------------------------------------------------------------------
// Projection GEMM: xw = x@kernel + bias0 (+bias1 folded for z,r).
// Output layout identical to R8 (permuted for gru per-lane loads):
//   region16 (64MB/dir): [bg(4)][t(1024)][wt(16)][lane_t(64)][8 halves]
//   region8  (32MB/dir, at +64MB): [bg][t][wt][lane_t][4 halves]
//   lane_t = hi_t*16 + (col&15), slots i_t = b&3, hi_t = (b&15)>>2.
// M-TILING: block = {4 batch rows (bg,hi_t) x 16 t} x 128 cols, so each
// block owns whole 16B/8B chunks -> packed dwordx2 stores (v_cvt_pkrtz),
// 8 stores/thread instead of 32 scalar u16.
// Row mapping: rr = w*16 + hi*4 + i  ->  t = tbase16 + w*4 + hi, b_loc = i.
// ---------------------------------------------------------------------------
__global__ __launch_bounds__(256) void proj_kernel(
    const float* __restrict__ x, const short* __restrict__ kT,
    const float* __restrict__ bias_f, const float* __restrict__ bias_b,
    char* __restrict__ xwp_f, char* __restrict__ xwp_b)
{
    __shared__ short lA[64][264];
    __shared__ short lB[128][264];

    const int tid = threadIdx.x;
    const int bt   = blockIdx.x;           // 0..1023
    const int tbase16 = (bt >> 4) * 16;    // 16-t tile
    const int bg   = (bt & 15) >> 2;
    const int hi_t = bt & 3;
    const int n0 = blockIdx.y * 128;

    // stage A: 64 rows = (b_loc = r&3, t_loc = r>>2), coalesced per row
#pragma unroll
    for (int rep = 0; rep < 16; ++rep) {
        int lin = rep * 256 + tid;
        int r = lin >> 6;
        int c4 = lin & 63;
        int bb = bg * 16 + hi_t * 4 + (r & 3);
        int tt = tbase16 + (r >> 2);
        float4 v = *(const float4*)(x + ((size_t)bb * 1024 + tt) * 256 + c4 * 4);
        short4 s;
        s.x = f2bf(v.x); s.y = f2bf(v.y); s.z = f2bf(v.z); s.w = f2bf(v.w);
        *(short4*)&lA[r][c4 * 4] = s;
    }
#pragma unroll
    for (int rep = 0; rep < 16; ++rep) {
        int lin = rep * 256 + tid;
        int r = lin >> 5;
        int c8 = lin & 31;
        uint4 v = *(const uint4*)(kT + (size_t)(n0 + r) * 256 + c8 * 8);
        *(uint4*)&lB[r][c8 * 8] = v;
    }
    __syncthreads();

    const int w = tid >> 6, l = tid & 63;
    const int l15 = l & 15, hi = l >> 4;

    bf16x8 a[8];
#pragma unroll
    for (int kt = 0; kt < 8; ++kt)
        a[kt] = *(const bf16x8*)&lA[w * 16 + l15][kt * 32 + hi * 8];

    const int t_row   = tbase16 + w * 4 + hi;     // this lane's t (all i share)
    const int lane_t  = hi_t * 16 + l15;

#pragma unroll
    for (int j = 0; j < 8; ++j) {
        f32x4 acc = {0.f, 0.f, 0.f, 0.f};
#pragma unroll
        for (int kt = 0; kt < 8; ++kt) {
            bf16x8 b = *(const bf16x8*)&lB[j * 16 + l15][kt * 32 + hi * 8];
            acc = __builtin_amdgcn_mfma_f32_16x16x32_bf16(a[kt], b, acc, 0, 0, 0);
        }
        int ng   = n0 + j * 16;            // uniform per j (l15 only in low 4)
        int dirb = ng >= 768;
        int nn0  = ng - (dirb ? 768 : 0);
        int g    = nn0 >> 8;               // 0=z, 1=r, 2=h
        int wtj  = (nn0 & 255) >> 4;
        const float* bias = dirb ? bias_b : bias_f;
        char* basep = dirb ? xwp_b : xwp_f;
        int nn = nn0 + l15;
        float badd = bias[nn] + ((nn < 512) ? bias[768 + nn] : 0.f);

        f16x2 lo2 = __builtin_amdgcn_cvt_pkrtz(acc[0] + badd, acc[1] + badd);
        f16x2 hi2 = __builtin_amdgcn_cvt_pkrtz(acc[2] + badd, acc[3] + badd);
        uint2 pk;
        pk.x = __builtin_bit_cast(unsigned, lo2);
        pk.y = __builtin_bit_cast(unsigned, hi2);

        if (g < 2) {
            *(uint2*)(basep + ((size_t)bg << 24) + ((size_t)t_row << 14)
                      + (wtj << 10) + (lane_t << 4) + (g * 8)) = pk;
        } else {
            *(uint2*)(basep + 67108864u + ((size_t)bg << 23)
                      + ((size_t)t_row << 13) + (wtj << 9) + (lane_t << 3)) = pk;
        }
    }
}

// ---------------------------------------------------------------------------
// Recurrence: 8 blocks (2 dirs x 4 groups of 16 batch rows), 1024 threads.
// BYTE-IDENTICAL to R8 (proven 1525-1531 us, absmax 0.0117).
// ---------------------------------------------------------------------------
#define GRU_STEP(PR, PW)                                                     \
  {                                                                          \
    uint4  xv16 = *(const uint4*)xp16;  xp16 += step16;                      \
    uint2  xv8  = *(const uint2*)xp8;   xp8  += step8;                       \
    unsigned bbase = 0;                                                      \
    asm volatile("" : "+v"(bbase));   /* defeat cross-step LDS-read hoist */ \
    f32x4 az = {0.f,0.f,0.f,0.f}, ar = {0.f,0.f,0.f,0.f},                    \
          ah = {0.f,0.f,0.f,0.f};                                           \
    _Pragma("unroll") for (int kt = 0; kt < 8; ++kt) {                       \
      bf16x8 aq = *(const bf16x8*)((const char*)hfrag + (PR)*8192            \
                                   + kt * 1024 + l * 16);                    \
      bf16x8 bh;                                                             \
      if (kt < 5) bh = Bh[kt];                                               \
      else bh = *(const bf16x8*)((const char*)bfrag + bbase                  \
                                 + (kt - 5) * 16384 + w * 1024 + l * 16);    \
      az = __builtin_amdgcn_mfma_f32_16x16x32_bf16(aq, Bz[kt], az, 0,0,0);   \
      ar = __builtin_amdgcn_mfma_f32_16x16x32_bf16(aq, Br[kt], ar, 0,0,0);   \
      ah = __builtin_amdgcn_mfma_f32_16x16x32_bf16(aq, bh, ah, 0,0,0);       \
    }                                                                        \
    const __half* hx  = (const __half*)&xv16;                                \
    const __half* hx8 = (const __half*)&xv8;                                 \
    float hn[4];                                                             \
    _Pragma("unroll") for (int i = 0; i < 4; ++i) {                          \
      float zi  = fast_rcp(1.f + fast_exp(-(__half2float(hx[i]) + az[i])));  \
      float rri = fast_rcp(1.f + fast_exp(-(__half2float(hx[4+i]) + ar[i])));\
      float pre = __half2float(hx8[i]) + rri * (ah[i] + b1h);                \
      float sg  = fast_rcp(1.f + fast_exp(-2.f * pre));                      \
      float hh  = 2.f * sg - 1.f;                                            \
      float h2  = hh + zi * (hold[i] - hh);                                  \
      hold[i] = h2;  hn[i] = h2;                                             \
      opbase[i * 524288] = h2;                                               \
    }                                                                        \
    unsigned pk0, pk1;                                                       \
    asm("v_cvt_pk_bf16_f32 %0, %1, %2" : "=v"(pk0) : "v"(hn[0]), "v"(hn[1]));\
    asm("v_cvt_pk_bf16_f32 %0, %1, %2" : "=v"(pk1) : "v"(hn[2]), "v"(hn[3]));\
    {                                                                        \
      char* hb = (char*)hfrag + (PW)*8192 + wb;                              \
      *(short*)(hb)      = (short)(pk0 & 0xffff);                            \
      *(short*)(hb + 16) = (short)(pk0 >> 16);                               \
      *(short*)(hb + 32) = (short)(pk1 & 0xffff);                            \
      *(short*)(hb + 48) = (short)(pk1 >> 16);                               \
    }                                                                        \
    opbase += ostep;                                                         \
    asm volatile("s_waitcnt lgkmcnt(0)\n\ts_barrier" ::: "memory");          \
  }

__global__ __launch_bounds__(1024) void gru_kernel(
    const char* __restrict__ xwp_f, const char* __restrict__ xwp_b,
    const short* __restrict__ recT_f, const short* __restrict__ recT_b,
    const float* __restrict__ bias_f, const float* __restrict__ bias_b,
    float* __restrict__ out)
{
    __shared__ short hfrag[2][8][64][8];      // h in A-frag layout, 16KB
    __shared__ short bfrag[3][16][64][8];     // offloaded Bh[5..7], 48KB

    const int tid = threadIdx.x;
    const int w = tid >> 6, l = tid & 63;
    const int l15 = l & 15, hi = l >> 4;
    const int dir = blockIdx.x >> 2;
    const int bg  = blockIdx.x & 3;
    const int b0  = bg * 16;

    const char*  xwp  = dir ? xwp_b  : xwp_f;
    const short* recT = dir ? recT_b : recT_f;
    const float* bias = dir ? bias_b : bias_f;

    const int cg = w * 16 + l15;
    const float b1h = bias[768 + 512 + cg];

    // zero both hfrag buffers (16KB = 1024 x int4)
    ((int4*)hfrag)[tid] = make_int4(0, 0, 0, 0);

    // rec-kernel B fragments: 21 to registers, 3 (Bh[5..7]) to LDS
    const char* recTc = (const char*)recT;
    unsigned offz = (((unsigned)(cg)       * 256u) + hi * 8u) * 2u;
    unsigned offr = (((unsigned)(256 + cg) * 256u) + hi * 8u) * 2u;
    unsigned offh = (((unsigned)(512 + cg) * 256u) + hi * 8u) * 2u;
    bf16x8 Bz[8], Br[8], Bh[5];
#pragma unroll
    for (int kt = 0; kt < 8; ++kt) {
        Bz[kt] = *(const bf16x8*)(recTc + offz + kt * 64);
        Br[kt] = *(const bf16x8*)(recTc + offr + kt * 64);
    }
#pragma unroll
    for (int kt = 0; kt < 5; ++kt)
        Bh[kt] = *(const bf16x8*)(recTc + offh + kt * 64);
#pragma unroll
    for (int kt = 5; kt < 8; ++kt) {
        bf16x8 tmp = *(const bf16x8*)(recTc + offh + kt * 64);
        *(bf16x8*)((char*)bfrag + (kt - 5) * 16384 + w * 1024 + l * 16) = tmp;
    }

    // xw per-lane streaming pointers (permuted layout)
    const int t0 = dir ? 1023 : 0;
    const long step16 = dir ? -16384 : 16384;
    const long step8  = dir ? -8192  : 8192;
    const char* xp16 = xwp + ((size_t)bg << 24) + ((size_t)t0 << 14)
                       + (w << 10) + (l << 4);
    const char* xp8  = xwp + 67108864u + ((size_t)bg << 23) + ((size_t)t0 << 13)
                       + (w << 9) + (l << 3);

    // out: rows b0+hi*4+i, column dir*256+cg, time t
    const long ostep = dir ? -512 : 512;
    float* opbase = out + (size_t)(b0 + hi * 4) * 524288 + (size_t)t0 * 512
                    + (size_t)dir * 256 + cg;

    // h-write byte offset within an hfrag buffer (A-frag position of (row, cg))
    const unsigned wb = (unsigned)(cg >> 5) * 1024u
                      + ((((unsigned)cg >> 3) & 3u) * 16u) * 16u
                      + (unsigned)(hi * 4) * 16u + ((unsigned)(l15 & 7)) * 2u;

    f32x4 hold = {0.f, 0.f, 0.f, 0.f};
    __syncthreads();      // hfrag zeros + bfrag writes visible

    for (int su = 0; su < 512; ++su) {
        GRU_STEP(0, 1)
        GRU_STEP(1, 0)
    }
}

// ---------------------------------------------------------------------------
extern "C" void kernel_launch(void* const* d_in, const int* in_sizes, int n_in,
                              void* d_out, int out_size, void* d_ws, size_t ws_size,
                              hipStream_t stream) {
    const float* x   = (const float*)d_in[0];
    const float* kf  = (const float*)d_in[1];
    const float* rf  = (const float*)d_in[2];
    const float* bf_ = (const float*)d_in[3];
    const float* kb  = (const float*)d_in[4];
    const float* rb  = (const float*)d_in[5];
    const float* bb_ = (const float*)d_in[6];

    char* ws = (char*)d_ws;
    char* xwp_f = ws;                                 // 96MB permuted xw (fwd)
    char* xwp_b = ws + 100663296;                     // 96MB permuted xw (bwd)
    short* rTf  = (short*)(ws + 201326592);           // 768*256 bf16
    short* rTb  = (short*)(ws + 201719808);
    short* kT   = (short*)(ws + 202113024);           // 1536*256 bf16
    float* out  = (float*)d_out;

    hipLaunchKernelGGL(prep_kernel, dim3(1536), dim3(256), 0, stream,
                       kf, kb, rf, rb, kT, rTf, rTb);
    hipLaunchKernelGGL(proj_kernel, dim3(1024, 12), dim3(256), 0, stream,
                       x, kT, bf_, bb_, xwp_f, xwp_b);
    hipLaunchKernelGGL(gru_kernel, dim3(8), dim3(1024), 0, stream,
                       xwp_f, xwp_b, rTf, rTb, bf_, bb_, out);
}